// Round 5
// baseline (388.836 us; speedup 1.0000x reference)
//
#include <hip/hip_runtime.h>
#include <cstdint>
#include <cstddef>

#define T_TOK 64
#define K_IN 4096
#define N_OUT 14336
#define SPLITK 16
#define KCHUNK (K_IN / SPLITK)        // 256 k per block
#define KSTEPS (KCHUNK / 32)          // 8 MFMA k-steps per block

typedef __attribute__((ext_vector_type(8))) short bf16x8;
typedef __attribute__((ext_vector_type(4))) float f32x4;

static __device__ __forceinline__ unsigned short bf16_rne(float f) {
    unsigned u = __builtin_bit_cast(unsigned, f);
    unsigned r = (u + 0x7fffu + ((u >> 16) & 1u)) >> 16;
    return (unsigned short)r;
}

// Kernel 1: x (fp32) -> bf16 copy in ws + per-token row sums.
__global__ __launch_bounds__(256) void prep_kernel(const float* __restrict__ x,
                                                   unsigned short* __restrict__ xbf,
                                                   float* __restrict__ rowsum) {
    const int row = blockIdx.x;
    const int t = threadIdx.x;
    const float4* x4 = (const float4*)(x + (size_t)row * K_IN);
    float s = 0.f;
#pragma unroll
    for (int i = 0; i < 4; i++) {
        float4 v = x4[i * 256 + t];
        s += v.x + v.y + v.z + v.w;
        ushort4 h;
        h.x = bf16_rne(v.x); h.y = bf16_rne(v.y);
        h.z = bf16_rne(v.z); h.w = bf16_rne(v.w);
        *(ushort4*)(xbf + (size_t)row * K_IN + (size_t)(i * 256 + t) * 4) = h;
    }
#pragma unroll
    for (int off = 32; off > 0; off >>= 1) s += __shfl_down(s, off, 64);
    __shared__ float part[4];
    const int wave = t >> 6, lane = t & 63;
    if (lane == 0) part[wave] = s;
    __syncthreads();
    if (t == 0) rowsum[row] = part[0] + part[1] + part[2] + part[3];
}

// Kernel 2: initialize out with bias + rowsum*u. Grid (N_OUT/4/256, T_TOK).
__global__ __launch_bounds__(256) void init_kernel(const float* __restrict__ rowsum,
                                                   const float* __restrict__ u,
                                                   const float* __restrict__ bias,
                                                   float* __restrict__ out) {
    const int t = blockIdx.y;
    const int n4 = blockIdx.x * 256 + threadIdx.x;
    const float rs = rowsum[t];
    float4 b = ((const float4*)bias)[n4];
    float4 uu = ((const float4*)u)[n4];
    float4 o;
    o.x = b.x + rs * uu.x; o.y = b.y + rs * uu.y;
    o.z = b.z + rs * uu.z; o.w = b.w + rs * uu.w;
    ((float4*)(out + (size_t)t * N_OUT))[n4] = o;
}

// Kernel 3: split-K streaming int4-dequant GEMM, 2 cols/lane (dwordx2 B loads).
// Grid: (N_OUT/128, SPLITK) = (112, 16) = 1792 blocks x 256 threads (4 waves).
// Wave w owns 32 cols: colbase = blk.x*128 + w*32, lane cols {colbase+2r, +2r+1}
// (even/odd strips map to two MFMA column tiles; epilogue un-permutes).
// All 64 token rows via 2 strips x 4 M-tiles = 8 MFMAs per 32-k step.
// B: per-lane int2 global loads (512 B per wave-instr, every byte used once).
// A: bf16 x from ws (L2-hot), 16 B/lane. Register double-buffer; no LDS.
__global__ __launch_bounds__(256, 3) void gemm_kernel(const unsigned short* __restrict__ xbf,
                                                      const int* __restrict__ W,
                                                      const float* __restrict__ scales,
                                                      float* __restrict__ out) {
    const int tid = threadIdx.x;
    const int wave = tid >> 6;
    const int lane = tid & 63;
    const int q = lane >> 4;       // quad: k-offset q*8 in A/B frags
    const int r = lane & 15;       // MFMA column index within a strip
    const int col0 = blockIdx.x * 128 + wave * 32 + 2 * r;   // even col (strip 0)
    const int kbase = blockIdx.y * KCHUNK;

    const int* __restrict__ wptr = W + (size_t)kbase * N_OUT + col0;  // +j*N_OUT per k
    const float* __restrict__ sptr = scales + col0;
    const unsigned short* __restrict__ xr = xbf + (size_t)r * K_IN + kbase;

    f32x4 acc[2][4];
#pragma unroll
    for (int s = 0; s < 2; s++)
#pragma unroll
        for (int mt = 0; mt < 4; mt++) acc[s][mt] = f32x4{0.f, 0.f, 0.f, 0.f};

    int4 abuf[2][4];
    int2 bbuf[2][8];       // 8 k x 2 cols
    float2 sbuf[2];

    // prologue: load step 0
    {
        const int base = q * 8;
        sbuf[0] = *(const float2*)(sptr + (size_t)(kbase / 128) * N_OUT);
#pragma unroll
        for (int j = 0; j < 8; j++)
            bbuf[0][j] = *(const int2*)(wptr + (size_t)(base + j) * N_OUT);
#pragma unroll
        for (int mt = 0; mt < 4; mt++)
            abuf[0][mt] = *(const int4*)(xr + (size_t)mt * 16 * K_IN + base);
    }

    for (int ks = 0; ks < KSTEPS; ks++) {
        const int cur = ks & 1;
        if (ks + 1 < KSTEPS) {
            const int nxt = cur ^ 1;
            const int base = (ks + 1) * 32 + q * 8;
            sbuf[nxt] = *(const float2*)(sptr + (size_t)((kbase + (ks + 1) * 32) / 128) * N_OUT);
#pragma unroll
            for (int j = 0; j < 8; j++)
                bbuf[nxt][j] = *(const int2*)(wptr + (size_t)(base + j) * N_OUT);
#pragma unroll
            for (int mt = 0; mt < 4; mt++)
                abuf[nxt][mt] = *(const int4*)(xr + (size_t)mt * 16 * K_IN + base);
        }

        // dequant current B ints -> two bf16 fragments (even/odd col strips)
        const float sc0 = sbuf[cur].x, sc1 = sbuf[cur].y;
        bf16x8 bf0, bf1;
#pragma unroll
        for (int j = 0; j < 8; j++) {
            bf0[j] = (short)bf16_rne((float)bbuf[cur][j].x * sc0);
            bf1[j] = (short)bf16_rne((float)bbuf[cur][j].y * sc1);
        }

#pragma unroll
        for (int mt = 0; mt < 4; mt++) {
            acc[0][mt] = __builtin_amdgcn_mfma_f32_16x16x32_bf16(
                __builtin_bit_cast(bf16x8, abuf[cur][mt]), bf0, acc[0][mt], 0, 0, 0);
            acc[1][mt] = __builtin_amdgcn_mfma_f32_16x16x32_bf16(
                __builtin_bit_cast(bf16x8, abuf[cur][mt]), bf1, acc[1][mt], 0, 0, 0);
        }
    }

    // epilogue: atomic accumulate partials (C/D layout: row = q*4+i, col index r)
#pragma unroll
    for (int mt = 0; mt < 4; mt++) {
#pragma unroll
        for (int i = 0; i < 4; i++) {
            const int t = mt * 16 + q * 4 + i;
            float* op = out + (size_t)t * N_OUT + col0;
            atomicAdd(op, acc[0][mt][i]);
            atomicAdd(op + 1, acc[1][mt][i]);
        }
    }
}

extern "C" void kernel_launch(void* const* d_in, const int* in_sizes, int n_in,
                              void* d_out, int out_size, void* d_ws, size_t ws_size,
                              hipStream_t stream) {
    const float* x      = (const float*)d_in[0];
    const int*   W      = (const int*)d_in[1];
    const float* scales = (const float*)d_in[2];
    const float* u      = (const float*)d_in[3];
    const float* bias   = (const float*)d_in[4];
    float* out = (float*)d_out;

    unsigned short* xbf = (unsigned short*)d_ws;                        // 64*4096*2 = 512 KB
    float* rowsum = (float*)((char*)d_ws + (size_t)T_TOK * K_IN * 2);   // 64 floats

    prep_kernel<<<T_TOK, 256, 0, stream>>>(x, xbf, rowsum);
    init_kernel<<<dim3(N_OUT / 4 / 256, T_TOK), 256, 0, stream>>>(rowsum, u, bias, out);
    gemm_kernel<<<dim3(N_OUT / 128, SPLITK), 256, 0, stream>>>(xbf, W, scales, out);
}

// Round 7
// 387.409 us; speedup vs baseline: 1.0037x; 1.0037x over previous
//
#include <hip/hip_runtime.h>
#include <cstdint>
#include <cstddef>

#define T_TOK 64
#define K_IN 4096
#define N_OUT 14336
#define SPLITK 16
#define KCHUNK (K_IN / SPLITK)        // 256 k per block
#define KSTEPS (KCHUNK / 32)          // 8 MFMA k-steps per block (fully unrolled)

typedef __attribute__((ext_vector_type(8))) short bf16x8;
typedef __attribute__((ext_vector_type(4))) float f32x4;

static __device__ __forceinline__ unsigned short bf16_rne(float f) {
    unsigned u = __builtin_bit_cast(unsigned, f);
    unsigned r = (u + 0x7fffu + ((u >> 16) & 1u)) >> 16;
    return (unsigned short)r;
}

// Kernel 1: x (fp32) -> bf16 copy in ws + per-token row sums.
__global__ __launch_bounds__(256) void prep_kernel(const float* __restrict__ x,
                                                   unsigned short* __restrict__ xbf,
                                                   float* __restrict__ rowsum) {
    const int row = blockIdx.x;
    const int t = threadIdx.x;
    const float4* x4 = (const float4*)(x + (size_t)row * K_IN);
    float s = 0.f;
#pragma unroll
    for (int i = 0; i < 4; i++) {
        float4 v = x4[i * 256 + t];
        s += v.x + v.y + v.z + v.w;
        ushort4 h;
        h.x = bf16_rne(v.x); h.y = bf16_rne(v.y);
        h.z = bf16_rne(v.z); h.w = bf16_rne(v.w);
        *(ushort4*)(xbf + (size_t)row * K_IN + (size_t)(i * 256 + t) * 4) = h;
    }
#pragma unroll
    for (int off = 32; off > 0; off >>= 1) s += __shfl_down(s, off, 64);
    __shared__ float part[4];
    const int wave = t >> 6, lane = t & 63;
    if (lane == 0) part[wave] = s;
    __syncthreads();
    if (t == 0) rowsum[row] = part[0] + part[1] + part[2] + part[3];
}

// Kernel 2: initialize out with bias + rowsum*u. Grid (N_OUT/4/256, T_TOK).
__global__ __launch_bounds__(256) void init_kernel(const float* __restrict__ rowsum,
                                                   const float* __restrict__ u,
                                                   const float* __restrict__ bias,
                                                   float* __restrict__ out) {
    const int t = blockIdx.y;
    const int n4 = blockIdx.x * 256 + threadIdx.x;
    const float rs = rowsum[t];
    float4 b = ((const float4*)bias)[n4];
    float4 uu = ((const float4*)u)[n4];
    float4 o;
    o.x = b.x + rs * uu.x; o.y = b.y + rs * uu.y;
    o.z = b.z + rs * uu.z; o.w = b.w + rs * uu.w;
    ((float4*)(out + (size_t)t * N_OUT))[n4] = o;
}

// Kernel 3: split-K streaming int4-dequant GEMM, 2 cols/lane (dwordx2 B loads).
// Grid: (N_OUT/128, SPLITK) = (112, 16) = 1792 blocks x 256 threads (4 waves).
// K-loop is FULLY UNROLLED so the double-buffer arrays get static indices and
// live in VGPRs (round 5: dynamic loop -> VGPR_Count=48, prefetch serialized).
__global__ __launch_bounds__(256, 3) void gemm_kernel(const unsigned short* __restrict__ xbf,
                                                      const int* __restrict__ W,
                                                      const float* __restrict__ scales,
                                                      float* __restrict__ out) {
    const int tid = threadIdx.x;
    const int wave = tid >> 6;
    const int lane = tid & 63;
    const int q = lane >> 4;       // quad: k-offset q*8 in A/B frags
    const int r = lane & 15;       // MFMA column index within a strip
    const int col0 = blockIdx.x * 128 + wave * 32 + 2 * r;   // even col (strip 0)
    const int kbase = blockIdx.y * KCHUNK;

    const int* __restrict__ wptr = W + (size_t)kbase * N_OUT + col0;  // +j*N_OUT per k
    const float* __restrict__ sptr = scales + col0;
    const unsigned short* __restrict__ xr = xbf + (size_t)r * K_IN + kbase;

    f32x4 acc[2][4];
#pragma unroll
    for (int s = 0; s < 2; s++)
#pragma unroll
        for (int mt = 0; mt < 4; mt++) acc[s][mt] = f32x4{0.f, 0.f, 0.f, 0.f};

    int4 abuf[2][4];
    int2 bbuf[2][8];       // 8 k x 2 cols
    float2 sbuf[2];

    // prologue: load step 0
    {
        const int base = q * 8;
        sbuf[0] = *(const float2*)(sptr + (size_t)(kbase / 128) * N_OUT);
#pragma unroll
        for (int j = 0; j < 8; j++)
            bbuf[0][j] = *(const int2*)(wptr + (size_t)(base + j) * N_OUT);
#pragma unroll
        for (int mt = 0; mt < 4; mt++)
            abuf[0][mt] = *(const int4*)(xr + (size_t)mt * 16 * K_IN + base);
    }

#pragma unroll
    for (int ks = 0; ks < KSTEPS; ks++) {
        const int cur = ks & 1;
        if (ks + 1 < KSTEPS) {
            const int nxt = cur ^ 1;
            const int base = (ks + 1) * 32 + q * 8;
            sbuf[nxt] = *(const float2*)(sptr + (size_t)((kbase + (ks + 1) * 32) / 128) * N_OUT);
#pragma unroll
            for (int j = 0; j < 8; j++)
                bbuf[nxt][j] = *(const int2*)(wptr + (size_t)(base + j) * N_OUT);
#pragma unroll
            for (int mt = 0; mt < 4; mt++)
                abuf[nxt][mt] = *(const int4*)(xr + (size_t)mt * 16 * K_IN + base);
        }

        // dequant current B ints -> two bf16 fragments (even/odd col strips)
        const float sc0 = sbuf[cur].x, sc1 = sbuf[cur].y;
        bf16x8 bf0, bf1;
#pragma unroll
        for (int j = 0; j < 8; j++) {
            bf0[j] = (short)bf16_rne((float)bbuf[cur][j].x * sc0);
            bf1[j] = (short)bf16_rne((float)bbuf[cur][j].y * sc1);
        }

#pragma unroll
        for (int mt = 0; mt < 4; mt++) {
            acc[0][mt] = __builtin_amdgcn_mfma_f32_16x16x32_bf16(
                __builtin_bit_cast(bf16x8, abuf[cur][mt]), bf0, acc[0][mt], 0, 0, 0);
            acc[1][mt] = __builtin_amdgcn_mfma_f32_16x16x32_bf16(
                __builtin_bit_cast(bf16x8, abuf[cur][mt]), bf1, acc[1][mt], 0, 0, 0);
        }
    }

    // epilogue: atomic accumulate partials (C/D layout: row = q*4+i, col index r)
#pragma unroll
    for (int mt = 0; mt < 4; mt++) {
#pragma unroll
        for (int i = 0; i < 4; i++) {
            const int t = mt * 16 + q * 4 + i;
            float* op = out + (size_t)t * N_OUT + col0;
            atomicAdd(op, acc[0][mt][i]);
            atomicAdd(op + 1, acc[1][mt][i]);
        }
    }
}

extern "C" void kernel_launch(void* const* d_in, const int* in_sizes, int n_in,
                              void* d_out, int out_size, void* d_ws, size_t ws_size,
                              hipStream_t stream) {
    const float* x      = (const float*)d_in[0];
    const int*   W      = (const int*)d_in[1];
    const float* scales = (const float*)d_in[2];
    const float* u      = (const float*)d_in[3];
    const float* bias   = (const float*)d_in[4];
    float* out = (float*)d_out;

    unsigned short* xbf = (unsigned short*)d_ws;                        // 64*4096*2 = 512 KB
    float* rowsum = (float*)((char*)d_ws + (size_t)T_TOK * K_IN * 2);   // 64 floats

    prep_kernel<<<T_TOK, 256, 0, stream>>>(x, xbf, rowsum);
    init_kernel<<<dim3(N_OUT / 4 / 256, T_TOK), 256, 0, stream>>>(rowsum, u, bias, out);
    gemm_kernel<<<dim3(N_OUT / 128, SPLITK), 256, 0, stream>>>(xbf, W, scales, out);
}

// Round 8
// 343.178 us; speedup vs baseline: 1.1330x; 1.1289x over previous
//
#include <hip/hip_runtime.h>
#include <cstdint>
#include <cstddef>

#define T_TOK 64
#define K_IN 4096
#define N_OUT 14336
#define SPLITK 16
#define KCHUNK 256                   // K per block (4096/16)
#define BK 32                        // k-rows per B stage
#define NSTAGES (KCHUNK / BK)        // 8
#define NCOLS 64                     // cols per block
#define A_STRIDE 528                 // 512 B row + 16 B pad (bank-spread for b128 reads)
#define A_BYTES (T_TOK * A_STRIDE)   // 33792
#define B_BYTES (BK * NCOLS * 4)     // 8192
#define LDS_TOTAL (A_BYTES + 2 * B_BYTES)  // 50176 (< 64 KB static cap; 3 blocks/CU)

typedef __attribute__((ext_vector_type(8))) short bf16x8;
typedef __attribute__((ext_vector_type(4))) float f32x4;

static __device__ __forceinline__ unsigned short bf16_rne(float f) {
    unsigned u = __builtin_bit_cast(unsigned, f);
    unsigned r = (u + 0x7fffu + ((u >> 16) & 1u)) >> 16;
    return (unsigned short)r;
}

// Kernel 1: x (fp32) -> bf16 copy in ws + per-token row sums.
__global__ __launch_bounds__(256) void prep_kernel(const float* __restrict__ x,
                                                   unsigned short* __restrict__ xbf,
                                                   float* __restrict__ rowsum) {
    const int row = blockIdx.x;
    const int t = threadIdx.x;
    const float4* x4 = (const float4*)(x + (size_t)row * K_IN);
    float s = 0.f;
#pragma unroll
    for (int i = 0; i < 4; i++) {
        float4 v = x4[i * 256 + t];
        s += v.x + v.y + v.z + v.w;
        ushort4 h;
        h.x = bf16_rne(v.x); h.y = bf16_rne(v.y);
        h.z = bf16_rne(v.z); h.w = bf16_rne(v.w);
        *(ushort4*)(xbf + (size_t)row * K_IN + (size_t)(i * 256 + t) * 4) = h;
    }
#pragma unroll
    for (int off = 32; off > 0; off >>= 1) s += __shfl_down(s, off, 64);
    __shared__ float part[4];
    const int wave = t >> 6, lane = t & 63;
    if (lane == 0) part[wave] = s;
    __syncthreads();
    if (t == 0) rowsum[row] = part[0] + part[1] + part[2] + part[3];
}

// Kernel 2: initialize out with bias + rowsum*u. Grid (N_OUT/4/256, T_TOK).
__global__ __launch_bounds__(256) void init_kernel(const float* __restrict__ rowsum,
                                                   const float* __restrict__ u,
                                                   const float* __restrict__ bias,
                                                   float* __restrict__ out) {
    const int t = blockIdx.y;
    const int n4 = blockIdx.x * 256 + threadIdx.x;
    const float rs = rowsum[t];
    float4 b = ((const float4*)bias)[n4];
    float4 uu = ((const float4*)u)[n4];
    float4 o;
    o.x = b.x + rs * uu.x; o.y = b.y + rs * uu.y;
    o.z = b.z + rs * uu.z; o.w = b.w + rs * uu.w;
    ((float4*)(out + (size_t)t * N_OUT))[n4] = o;
}

// Kernel 3: split-K int4-dequant GEMM with global_load_lds DMA streaming of W.
// Grid (224, 16) x 256 thr. Block = 64 cols x 256 k. A-slice (64 tok x 256 k bf16,
// 32 KB) staged to LDS ONCE (manual, padded). W streamed via async DMA into a
// double-buffered LDS tile (8 KB = 32 k x 64 cols), 8 stages, 1 barrier/stage.
// DMA has no VGPR dest -> scheduler cannot serialize it (rounds 5/7 failure mode).
__global__ __launch_bounds__(256) void gemm_kernel(const unsigned short* __restrict__ xbf,
                                                   const int* __restrict__ W,
                                                   const float* __restrict__ scales,
                                                   float* __restrict__ out) {
    __shared__ char lds[LDS_TOTAL];
    char* Alds = lds;

    const int tid = threadIdx.x;
    const int wave = tid >> 6;
    const int lane = tid & 63;
    const int q = lane >> 4;            // quad: k-offset q*8 in frags
    const int r = lane & 15;            // col within wave's 16-col strip / token row
    const int cb = blockIdx.x;
    const int kbase = blockIdx.y * KCHUNK;
    const int col = cb * NCOLS + wave * 16 + r;

    // two 128-group scales covering this block's 256-k chunk
    const int g0 = kbase >> 7;
    const float sc0 = scales[(size_t)g0 * N_OUT + col];
    const float sc1 = scales[(size_t)(g0 + 1) * N_OUT + col];

    // ---- stage A once: 64 rows x 512 B -> LDS rows of A_STRIDE
    {
        int4 av[8];
#pragma unroll
        for (int i = 0; i < 8; i++) {
            const int chunk = i * 256 + tid;           // 2048 chunks of 16 B
            const int row = chunk >> 5;
            const int cc = chunk & 31;
            av[i] = *(const int4*)(xbf + (size_t)row * K_IN + kbase + cc * 8);
        }
#pragma unroll
        for (int i = 0; i < 8; i++) {
            const int chunk = i * 256 + tid;
            const int row = chunk >> 5;
            const int cc = chunk & 31;
            *(int4*)(Alds + row * A_STRIDE + cc * 16) = av[i];
        }
    }

    // ---- B-stage DMA: 8 instrs x 1 KB (4 k-rows x 256 B each), 2 instrs/wave.
    // LDS dest = wave-uniform base + lane*16 (hardware-defined scatter).
    auto issue_stage = [&](int s) {
        char* Bbuf = lds + A_BYTES + (s & 1) * B_BYTES;
#pragma unroll
        for (int j = 0; j < 2; j++) {
            const int instr = wave * 2 + j;            // 0..7
            const int krow = kbase + s * BK + instr * 4 + (lane >> 4);
            const int* g = W + (size_t)krow * N_OUT + cb * NCOLS + (lane & 15) * 4;
            void* l = (void*)(Bbuf + instr * 1024);
            __builtin_amdgcn_global_load_lds(
                (const __attribute__((address_space(1))) void*)g,
                (__attribute__((address_space(3))) void*)l, 16, 0, 0);
        }
    };

    f32x4 acc[4];
#pragma unroll
    for (int mt = 0; mt < 4; mt++) acc[mt] = f32x4{0.f, 0.f, 0.f, 0.f};

    issue_stage(0);
    __syncthreads();    // A writes + own-wave DMA drained (vmcnt 0) + barrier

#pragma unroll
    for (int s = 0; s < NSTAGES; s++) {
        if (s + 1 < NSTAGES) issue_stage(s + 1);

        const char* Bbuf = lds + A_BYTES + (s & 1) * B_BYTES;
        const float scs = (s < 4) ? sc0 : sc1;        // group = (kbase + s*32)/128

        int bi[8];
#pragma unroll
        for (int j = 0; j < 8; j++)
            bi[j] = *(const int*)(Bbuf + (q * 8 + j) * 256 + (wave * 16 + r) * 4);
        bf16x8 bf;
#pragma unroll
        for (int j = 0; j < 8; j++) bf[j] = (short)bf16_rne((float)bi[j] * scs);

#pragma unroll
        for (int mt = 0; mt < 4; mt++) {
            bf16x8 af = *(const bf16x8*)(Alds + (r + mt * 16) * A_STRIDE + s * 64 + q * 16);
            acc[mt] = __builtin_amdgcn_mfma_f32_16x16x32_bf16(af, bf, acc[mt], 0, 0, 0);
        }
        __syncthreads();   // all waves done reading Bbuf; next stage's DMA landed
    }

    // epilogue: atomic accumulate partials (C/D layout: row = q*4+i, col = col)
#pragma unroll
    for (int mt = 0; mt < 4; mt++) {
#pragma unroll
        for (int i = 0; i < 4; i++) {
            const int t = mt * 16 + q * 4 + i;
            atomicAdd(out + (size_t)t * N_OUT + col, acc[mt][i]);
        }
    }
}

extern "C" void kernel_launch(void* const* d_in, const int* in_sizes, int n_in,
                              void* d_out, int out_size, void* d_ws, size_t ws_size,
                              hipStream_t stream) {
    const float* x      = (const float*)d_in[0];
    const int*   W      = (const int*)d_in[1];
    const float* scales = (const float*)d_in[2];
    const float* u      = (const float*)d_in[3];
    const float* bias   = (const float*)d_in[4];
    float* out = (float*)d_out;

    unsigned short* xbf = (unsigned short*)d_ws;                        // 64*4096*2 = 512 KB
    float* rowsum = (float*)((char*)d_ws + (size_t)T_TOK * K_IN * 2);   // 64 floats

    prep_kernel<<<T_TOK, 256, 0, stream>>>(x, xbf, rowsum);
    init_kernel<<<dim3(N_OUT / 4 / 256, T_TOK), 256, 0, stream>>>(rowsum, u, bias, out);
    gemm_kernel<<<dim3(N_OUT / NCOLS, SPLITK), 256, 0, stream>>>(xbf, W, scales, out);
}

// Round 9
// 342.253 us; speedup vs baseline: 1.1361x; 1.0027x over previous
//
#include <hip/hip_runtime.h>
#include <cstdint>
#include <cstddef>

#define T_TOK 64
#define K_IN 4096
#define N_OUT 14336
#define SPLITK 16
#define KCHUNK 256                   // K per block (4096/16)
#define BK 32                        // k-rows per B stage
#define NSTAGES (KCHUNK / BK)        // 8
#define NCOLS 64                     // cols per block (16 per wave)
#define DEPTH 4                      // B ring slots per wave
#define A_BYTES 32768                // 64 rows x 512 B, XOR-swizzled (no pad)
#define B_WAVE_BYTES (DEPTH * BK * 16 * 4)   // 8192 per wave
#define LDS_TOTAL (A_BYTES + 4 * B_WAVE_BYTES)  // 65536

typedef __attribute__((ext_vector_type(8))) short bf16x8;
typedef __attribute__((ext_vector_type(4))) float f32x4;

static __device__ __forceinline__ unsigned short bf16_rne(float f) {
    unsigned u = __builtin_bit_cast(unsigned, f);
    unsigned r = (u + 0x7fffu + ((u >> 16) & 1u)) >> 16;
    return (unsigned short)r;
}

// Kernel 1: x (fp32) -> bf16 copy in ws + per-token row sums.
__global__ __launch_bounds__(256) void prep_kernel(const float* __restrict__ x,
                                                   unsigned short* __restrict__ xbf,
                                                   float* __restrict__ rowsum) {
    const int row = blockIdx.x;
    const int t = threadIdx.x;
    const float4* x4 = (const float4*)(x + (size_t)row * K_IN);
    float s = 0.f;
#pragma unroll
    for (int i = 0; i < 4; i++) {
        float4 v = x4[i * 256 + t];
        s += v.x + v.y + v.z + v.w;
        ushort4 h;
        h.x = bf16_rne(v.x); h.y = bf16_rne(v.y);
        h.z = bf16_rne(v.z); h.w = bf16_rne(v.w);
        *(ushort4*)(xbf + (size_t)row * K_IN + (size_t)(i * 256 + t) * 4) = h;
    }
#pragma unroll
    for (int off = 32; off > 0; off >>= 1) s += __shfl_down(s, off, 64);
    __shared__ float part[4];
    const int wave = t >> 6, lane = t & 63;
    if (lane == 0) part[wave] = s;
    __syncthreads();
    if (t == 0) rowsum[row] = part[0] + part[1] + part[2] + part[3];
}

// Kernel 2: initialize out with bias + rowsum*u. Grid (N_OUT/4/256, T_TOK).
__global__ __launch_bounds__(256) void init_kernel(const float* __restrict__ rowsum,
                                                   const float* __restrict__ u,
                                                   const float* __restrict__ bias,
                                                   float* __restrict__ out) {
    const int t = blockIdx.y;
    const int n4 = blockIdx.x * 256 + threadIdx.x;
    const float rs = rowsum[t];
    float4 b = ((const float4*)bias)[n4];
    float4 uu = ((const float4*)u)[n4];
    float4 o;
    o.x = b.x + rs * uu.x; o.y = b.y + rs * uu.y;
    o.z = b.z + rs * uu.z; o.w = b.w + rs * uu.w;
    ((float4*)(out + (size_t)t * N_OUT))[n4] = o;
}

// Kernel 3: split-K int4-dequant GEMM, BARRIER-FREE K-loop.
// Grid (224, 16) x 256 thr. Block = 64 cols x 256 k; wave owns a private
// 16-col strip. B is DMA'd (global_load_lds) into a per-wave depth-4 LDS ring
// (2 KB/stage); the wave syncs on its own queue with s_waitcnt vmcnt(N)
// (never 0, no __syncthreads in the loop) -> 6 DMA instrs always in flight.
// A (64 tok x 256 k bf16, 32 KB) staged once, XOR-swizzled, one barrier total.
__global__ __launch_bounds__(256) void gemm_kernel(const unsigned short* __restrict__ xbf,
                                                   const int* __restrict__ W,
                                                   const float* __restrict__ scales,
                                                   float* __restrict__ out) {
    __shared__ char lds[LDS_TOTAL];
    char* Alds = lds;

    const int tid = threadIdx.x;
    const int wave = tid >> 6;
    const int lane = tid & 63;
    const int q = lane >> 4;            // quad: k-offset q*8 in frags
    const int r = lane & 15;            // col within wave strip / token row
    const int cb = blockIdx.x;
    const int kbase = blockIdx.y * KCHUNK;
    const int col = cb * NCOLS + wave * 16 + r;

    // two 128-group scales covering this block's 256-k chunk
    const int g0 = kbase >> 7;
    const float sc0 = scales[(size_t)g0 * N_OUT + col];
    const float sc1 = scales[(size_t)(g0 + 1) * N_OUT + col];

    // ---- stage A once: 64 rows x 512 B, chunk cc (16 B) stored at cc^(row&7)
    {
        int4 av[8];
#pragma unroll
        for (int i = 0; i < 8; i++) {
            const int chunk = i * 256 + tid;           // 2048 chunks of 16 B
            const int row = chunk >> 5;
            const int cc = chunk & 31;
            av[i] = *(const int4*)(xbf + (size_t)row * K_IN + kbase + cc * 8);
        }
#pragma unroll
        for (int i = 0; i < 8; i++) {
            const int chunk = i * 256 + tid;
            const int row = chunk >> 5;
            const int cc = chunk & 31;
            *(int4*)(Alds + row * 512 + (cc ^ (row & 7)) * 16) = av[i];
        }
    }
    __syncthreads();   // ONLY barrier: A visible to all waves (before DMA issues)

    char* Bring = lds + A_BYTES + wave * B_WAVE_BYTES;

    // per-wave B DMA: stage = 16 cols x 32 k = 2 KB = 2 instrs x 1 KB.
    // lane -> (k_local = lane>>2, colq = lane&3); LDS dest = base + lane*16
    // gives [k][col16] rows of 64 B. Global side matches: 64 B per k-row.
    auto issue_stage = [&](int s) {
        char* slot = Bring + (s & 3) * (BK * 64);
#pragma unroll
        for (int j = 0; j < 2; j++) {
            const int krow = kbase + s * BK + j * 16 + (lane >> 2);
            const int* g = W + (size_t)krow * N_OUT + cb * NCOLS + wave * 16 + (lane & 3) * 4;
            void* l = (void*)(slot + j * 1024);
            __builtin_amdgcn_global_load_lds(
                (const __attribute__((address_space(1))) void*)g,
                (__attribute__((address_space(3))) void*)l, 16, 0, 0);
        }
    };

    f32x4 acc[4];
#pragma unroll
    for (int mt = 0; mt < 4; mt++) acc[mt] = f32x4{0.f, 0.f, 0.f, 0.f};

    auto compute_stage = [&](int s) {
        const char* slot = Bring + (s & 3) * (BK * 64);
        const float scs = (s < 4) ? sc0 : sc1;        // group = (kbase+s*32)/128
        int bi[8];
#pragma unroll
        for (int jj = 0; jj < 8; jj++)
            bi[jj] = *(const int*)(slot + (q * 8 + jj) * 64 + r * 4);
        bf16x8 bf;
#pragma unroll
        for (int jj = 0; jj < 8; jj++) bf[jj] = (short)bf16_rne((float)bi[jj] * scs);
#pragma unroll
        for (int mt = 0; mt < 4; mt++) {
            const int row = r + mt * 16;
            bf16x8 af = *(const bf16x8*)(Alds + row * 512 + (((s * 4 + q) ^ (r & 7)) * 16));
            acc[mt] = __builtin_amdgcn_mfma_f32_16x16x32_bf16(af, bf, acc[mt], 0, 0, 0);
        }
    };

    // prologue: fill the ring (8 DMA instrs in flight)
    issue_stage(0); issue_stage(1); issue_stage(2); issue_stage(3);

    // vmcnt(N) waits until only N vm-ops outstanding; stage s needs its own 2
    // instrs done. simm16: lgkmcnt=15 (0xF00) | expcnt=7 (0x70) | vmcnt low bits.
#define GEMM_STAGE(S, WN)                                   \
    {                                                       \
        __builtin_amdgcn_s_waitcnt(0x0F70 | (WN));          \
        compute_stage(S);                                   \
        if ((S) + DEPTH < NSTAGES) issue_stage((S) + DEPTH);\
    }
    GEMM_STAGE(0, 6) GEMM_STAGE(1, 6) GEMM_STAGE(2, 6) GEMM_STAGE(3, 6)
    GEMM_STAGE(4, 6) GEMM_STAGE(5, 4) GEMM_STAGE(6, 2) GEMM_STAGE(7, 0)
#undef GEMM_STAGE

    // epilogue: atomic accumulate partials (C/D layout: row = q*4+i, col = col)
#pragma unroll
    for (int mt = 0; mt < 4; mt++) {
#pragma unroll
        for (int i = 0; i < 4; i++) {
            const int t = mt * 16 + q * 4 + i;
            atomicAdd(out + (size_t)t * N_OUT + col, acc[mt][i]);
        }
    }
}

extern "C" void kernel_launch(void* const* d_in, const int* in_sizes, int n_in,
                              void* d_out, int out_size, void* d_ws, size_t ws_size,
                              hipStream_t stream) {
    const float* x      = (const float*)d_in[0];
    const int*   W      = (const int*)d_in[1];
    const float* scales = (const float*)d_in[2];
    const float* u      = (const float*)d_in[3];
    const float* bias   = (const float*)d_in[4];
    float* out = (float*)d_out;

    unsigned short* xbf = (unsigned short*)d_ws;                        // 64*4096*2 = 512 KB
    float* rowsum = (float*)((char*)d_ws + (size_t)T_TOK * K_IN * 2);   // 64 floats

    prep_kernel<<<T_TOK, 256, 0, stream>>>(x, xbf, rowsum);
    init_kernel<<<dim3(N_OUT / 4 / 256, T_TOK), 256, 0, stream>>>(rowsum, u, bias, out);
    gemm_kernel<<<dim3(N_OUT / NCOLS, SPLITK), 256, 0, stream>>>(xbf, W, scales, out);
}